// Round 1
// baseline (965.744 us; speedup 1.0000x reference)
//
#include <hip/hip_runtime.h>

#define FIN 128
#define HID 64

// ---------------------------------------------------------------- degree ----
__global__ void count_deg(const int* __restrict__ dst, float* __restrict__ deg, int E) {
    int e = blockIdx.x * 256 + threadIdx.x;
    if (e < E) unsafeAtomicAdd(&deg[dst[e]], 1.0f);
}

__global__ void make_dinv(float* __restrict__ deg, int N) {
    int n = blockIdx.x * 256 + threadIdx.x;
    if (n < N) deg[n] = rsqrtf(deg[n] + 1.0f);
}

// ------------------------------------------------------- h0 = x @ W1 --------
// block = 256 threads, tile = 16 nodes. W1 (128x64, 32KB) + x-tile (16x128, 8KB) in LDS.
// thread owns (f0=f, f1=f+32) x (2 nodes): 4 FMA per 4 LDS reads, conflict-free.
__global__ void gemm1(const float* __restrict__ x, const float* __restrict__ W1,
                      float* __restrict__ h0, int N) {
    __shared__ float Ws[FIN * HID];
    __shared__ float xs[16 * FIN];
    const float4* W4 = (const float4*)W1;
    float4* Ws4 = (float4*)Ws;
#pragma unroll
    for (int j = 0; j < 8; ++j) Ws4[threadIdx.x + 256 * j] = W4[threadIdx.x + 256 * j];
    __syncthreads();

    int f0 = threadIdx.x & 31, f1 = f0 + 32;
    int slot = threadIdx.x >> 5;          // 0..7 -> node pair
    int n0 = slot * 2, n1 = n0 + 1;
    int ntiles = N >> 4;                  // N % 16 == 0 (N = 100000)
    for (int tile = blockIdx.x; tile < ntiles; tile += gridDim.x) {
        int base = tile << 4;
        const float4* xg = (const float4*)(x + (size_t)base * FIN);
        float4* xs4 = (float4*)xs;
        xs4[threadIdx.x]       = xg[threadIdx.x];
        xs4[threadIdx.x + 256] = xg[threadIdx.x + 256];
        __syncthreads();
        float a00 = 0.f, a01 = 0.f, a10 = 0.f, a11 = 0.f;
#pragma unroll 8
        for (int k = 0; k < FIN; ++k) {
            float w0 = Ws[k * HID + f0], w1 = Ws[k * HID + f1];
            float x0 = xs[n0 * FIN + k], x1 = xs[n1 * FIN + k];
            a00 += x0 * w0; a01 += x0 * w1;
            a10 += x1 * w0; a11 += x1 * w1;
        }
        size_t r0 = (size_t)(base + n0) * HID, r1 = (size_t)(base + n1) * HID;
        h0[r0 + f0] = a00; h0[r0 + f1] = a01;
        h0[r1 + f0] = a10; h0[r1 + f1] = a11;
        __syncthreads();
    }
}

// ------------------------------------------- edge scatter: agg[dst] += h[src]*coef
// wave per edge, lane = feature. Gather + atomic are both 256B coalesced.
__global__ void scatter_k(const float* __restrict__ hin, const int* __restrict__ src,
                          const int* __restrict__ dst, const float* __restrict__ dinv,
                          float* __restrict__ agg, int E) {
    unsigned tid = blockIdx.x * 256u + threadIdx.x;
    unsigned e = tid >> 6;
    if (e >= (unsigned)E) return;
    int f = tid & 63;
    int s = src[e], d = dst[e];
    float c = dinv[s] * dinv[d];
    float v = hin[(size_t)s * HID + f] * c;
    unsafeAtomicAdd(&agg[(size_t)d * HID + f], v);
}

// ------------------------------- h = relu(agg1 + h0*dinv^2 + b1), in-place over agg1
__global__ void relu_k(float* __restrict__ hb, const float* __restrict__ h0,
                       const float* __restrict__ dinv, const float* __restrict__ b1,
                       int N) {
    size_t tid = (size_t)blockIdx.x * 256 + threadIdx.x;
    if (tid >= (size_t)N * HID) return;
    int f = (int)(tid & 63);
    int n = (int)(tid >> 6);
    float di = dinv[n];
    float v = hb[tid] + h0[tid] * di * di + b1[f];
    hb[tid] = v > 0.f ? v : 0.f;
}

// ---------------- epilogue: Abar = agg2 + h*dinv^2 ; mu = Abar@Wmu+bmu ; ls = Abar@Wls+bls
// block = 4 waves, wave per node. Wc[k][j] packs Wmu (j<32) and Wls (j>=32) in LDS.
__global__ void final_k(const float* __restrict__ agg2, const float* __restrict__ h,
                        const float* __restrict__ dinv,
                        const float* __restrict__ Wmu, const float* __restrict__ bmu,
                        const float* __restrict__ Wls, const float* __restrict__ bls,
                        float* __restrict__ out, int N) {
    __shared__ float Wc[HID * 64];
    __shared__ float bc[64];
    __shared__ float ab[4][HID];
    for (int idx = threadIdx.x; idx < HID * 64; idx += 256) {
        int k = idx >> 6, j = idx & 63;
        Wc[idx] = (j < 32) ? Wmu[k * 32 + j] : Wls[k * 32 + (j - 32)];
    }
    if (threadIdx.x < 64) {
        int j = threadIdx.x;
        bc[j] = (j < 32) ? bmu[j] : bls[j - 32];
    }
    __syncthreads();

    int wave = threadIdx.x >> 6, lane = threadIdx.x & 63;
    int stride = gridDim.x * 4;
    int iters = (N + stride - 1) / stride;
    for (int it = 0; it < iters; ++it) {
        int n = blockIdx.x * 4 + wave + it * stride;
        bool act = n < N;
        if (act) {
            float di = dinv[n], d2 = di * di;
            ab[wave][lane] = agg2[(size_t)n * HID + lane] + h[(size_t)n * HID + lane] * d2;
        }
        __syncthreads();
        if (act) {
            float acc = bc[lane];
#pragma unroll 8
            for (int k = 0; k < HID; ++k) acc += ab[wave][k] * Wc[k * 64 + lane];
            int which = lane >> 5, o = lane & 31;
            out[(size_t)which * N * 32 + (size_t)n * 32 + o] = acc;
        }
        __syncthreads();
    }
}

// ---------------------------------------------------------------------------
extern "C" void kernel_launch(void* const* d_in, const int* in_sizes, int n_in,
                              void* d_out, int out_size, void* d_ws, size_t ws_size,
                              hipStream_t stream) {
    const float* x   = (const float*)d_in[0];
    const int*   ei  = (const int*)d_in[1];
    const float* W1  = (const float*)d_in[2];
    const float* b1  = (const float*)d_in[3];
    const float* Wmu = (const float*)d_in[4];
    const float* bmu = (const float*)d_in[5];
    const float* Wls = (const float*)d_in[6];
    const float* bls = (const float*)d_in[7];
    int N = in_sizes[0] / FIN;
    int E = in_sizes[1] / 2;
    const int* src = ei;
    const int* dst = ei + E;
    float* out = (float*)d_out;

    // workspace: deg/dinv [N] | bufA [N*64] (h0 -> agg2) | bufB [N*64] (agg1 -> h)
    float* deg  = (float*)d_ws;
    float* bufA = deg + N;
    float* bufB = bufA + (size_t)N * HID;

    hipMemsetAsync(deg, 0, (size_t)N * sizeof(float), stream);
    count_deg<<<(E + 255) / 256, 256, 0, stream>>>(dst, deg, E);
    make_dinv<<<(N + 255) / 256, 256, 0, stream>>>(deg, N);

    gemm1<<<1024, 256, 0, stream>>>(x, W1, bufA, N);

    hipMemsetAsync(bufB, 0, (size_t)N * HID * sizeof(float), stream);
    scatter_k<<<(int)(((size_t)E * 64 + 255) / 256), 256, 0, stream>>>(bufA, src, dst, deg, bufB, E);
    relu_k<<<(int)(((size_t)N * HID + 255) / 256), 256, 0, stream>>>(bufB, bufA, deg, b1, N);

    hipMemsetAsync(bufA, 0, (size_t)N * HID * sizeof(float), stream);
    scatter_k<<<(int)(((size_t)E * 64 + 255) / 256), 256, 0, stream>>>(bufB, src, dst, deg, bufA, E);

    final_k<<<1250, 256, 0, stream>>>(bufA, bufB, deg, Wmu, bmu, Wls, bls, out, N);
}

// Round 2
// 563.078 us; speedup vs baseline: 1.7151x; 1.7151x over previous
//
#include <hip/hip_runtime.h>

#define FIN 128
#define HID 64
#define SCAN_BS 1024

// ---------------------------------------------------------------- degree ----
__global__ void count_deg(const int* __restrict__ dst, int* __restrict__ deg, int E) {
    int e = blockIdx.x * 256 + threadIdx.x;
    if (e < E) atomicAdd(&deg[dst[e]], 1);
}

// ------------------------------------------------- prefix scan (3 kernels) --
__global__ void scan_blocks(const int* __restrict__ deg, int* __restrict__ row_ex,
                            int* __restrict__ partials, int N) {
    __shared__ int s[SCAN_BS];
    int t = threadIdx.x;
    int i = blockIdx.x * SCAN_BS + t;
    int v = (i < N) ? deg[i] : 0;
    s[t] = v;
    __syncthreads();
    for (int off = 1; off < SCAN_BS; off <<= 1) {
        int a = (t >= off) ? s[t - off] : 0;
        __syncthreads();
        s[t] += a;
        __syncthreads();
    }
    if (i < N) row_ex[i] = s[t] - v;            // block-local exclusive
    if (t == SCAN_BS - 1) partials[blockIdx.x] = s[t];
}

__global__ void scan_partials(int* __restrict__ partials, int nb) {
    __shared__ int s[128];
    int t = threadIdx.x;
    int v = (t < nb) ? partials[t] : 0;
    s[t] = v;
    __syncthreads();
    for (int off = 1; off < 128; off <<= 1) {
        int a = (t >= off) ? s[t - off] : 0;
        __syncthreads();
        s[t] += a;
        __syncthreads();
    }
    if (t < nb) partials[t] = s[t] - v;          // exclusive
}

__global__ void finalize_ptr(const int* __restrict__ deg, int* __restrict__ row_ex,
                             int* __restrict__ cursor, const int* __restrict__ partials,
                             float* __restrict__ dinv, int N) {
    int i = blockIdx.x * 256 + threadIdx.x;
    if (i >= N) return;
    int r = row_ex[i] + partials[i >> 10];
    row_ex[i] = r;      // row start
    cursor[i] = r;      // fill cursor; after fill_csr it equals row end
    dinv[i] = rsqrtf((float)deg[i] + 1.0f);
}

// ------------------------------------------------------------- CSR fill -----
__global__ void fill_csr(const int* __restrict__ src, const int* __restrict__ dst,
                         int* __restrict__ cursor, int* __restrict__ csr, int E) {
    int e = blockIdx.x * 256 + threadIdx.x;
    if (e >= E) return;
    int d = dst[e];
    int p = atomicAdd(&cursor[d], 1);
    csr[p] = src[e];
}

// ------------------------------------------------------- h0 = x @ W1 --------
__global__ void gemm1(const float* __restrict__ x, const float* __restrict__ W1,
                      float* __restrict__ h0, int N) {
    __shared__ float Ws[FIN * HID];
    __shared__ float xs[16 * FIN];
    const float4* W4 = (const float4*)W1;
    float4* Ws4 = (float4*)Ws;
#pragma unroll
    for (int j = 0; j < 8; ++j) Ws4[threadIdx.x + 256 * j] = W4[threadIdx.x + 256 * j];
    __syncthreads();

    int f0 = threadIdx.x & 31, f1 = f0 + 32;
    int slot = threadIdx.x >> 5;
    int n0 = slot * 2, n1 = n0 + 1;
    int ntiles = N >> 4;
    for (int tile = blockIdx.x; tile < ntiles; tile += gridDim.x) {
        int base = tile << 4;
        const float4* xg = (const float4*)(x + (size_t)base * FIN);
        float4* xs4 = (float4*)xs;
        xs4[threadIdx.x]       = xg[threadIdx.x];
        xs4[threadIdx.x + 256] = xg[threadIdx.x + 256];
        __syncthreads();
        float a00 = 0.f, a01 = 0.f, a10 = 0.f, a11 = 0.f;
#pragma unroll 8
        for (int k = 0; k < FIN; ++k) {
            float w0 = Ws[k * HID + f0], w1 = Ws[k * HID + f1];
            float x0 = xs[n0 * FIN + k], x1 = xs[n1 * FIN + k];
            a00 += x0 * w0; a01 += x0 * w1;
            a10 += x1 * w0; a11 += x1 * w1;
        }
        size_t r0 = (size_t)(base + n0) * HID, r1 = (size_t)(base + n1) * HID;
        h0[r0 + f0] = a00; h0[r0 + f1] = a01;
        h0[r1 + f0] = a10; h0[r1 + f1] = a11;
        __syncthreads();
    }
}

// --------------- pull pass 1: h = relu(dinv[d]*Σ h0[s]*dinv[s] + h0[d]*dinv² + b1)
// wave per node, lane = feature. Neighbor indices/coefs loaded cooperatively,
// broadcast via shfl; gathers are 256B coalesced.
__global__ void pull1(const float* __restrict__ h0, const int* __restrict__ row,
                      const int* __restrict__ rend, const int* __restrict__ csr,
                      const float* __restrict__ dinv, const float* __restrict__ b1,
                      float* __restrict__ h, int N) {
    int wave = threadIdx.x >> 6, lane = threadIdx.x & 63;
    int n = blockIdx.x * 4 + wave;
    if (n >= N) return;
    int start = row[n], end = rend[n];
    float acc = 0.f;
    for (int j0 = start; j0 < end; j0 += 64) {
        int cnt = min(64, end - j0);
        int s = (lane < cnt) ? csr[j0 + lane] : 0;
        float ds = (lane < cnt) ? dinv[s] : 0.f;
        for (int j = 0; j < cnt; ++j) {
            int sj = __shfl(s, j);
            float dsj = __shfl(ds, j);
            acc += h0[(size_t)sj * HID + lane] * dsj;
        }
    }
    float di = dinv[n];
    float v = acc * di + h0[(size_t)n * HID + lane] * di * di + b1[lane];
    h[(size_t)n * HID + lane] = v > 0.f ? v : 0.f;
}

// --------------- pull pass 2 + output matvecs, fused.
// abar = dinv[d]*Σ h[s]*dinv[s] + h[d]*dinv² ; out = [abar@Wmu+bmu | abar@Wls+bls]
__global__ void pull2_final(const float* __restrict__ h, const int* __restrict__ row,
                            const int* __restrict__ rend, const int* __restrict__ csr,
                            const float* __restrict__ dinv,
                            const float* __restrict__ Wmu, const float* __restrict__ bmu,
                            const float* __restrict__ Wls, const float* __restrict__ bls,
                            float* __restrict__ out, int N) {
    __shared__ float Wc[HID * 64];
    __shared__ float bc[64];
    __shared__ float ab[4][HID];
    for (int idx = threadIdx.x; idx < HID * 64; idx += 256) {
        int k = idx >> 6, j = idx & 63;
        Wc[idx] = (j < 32) ? Wmu[k * 32 + j] : Wls[k * 32 + (j - 32)];
    }
    if (threadIdx.x < 64) {
        int j = threadIdx.x;
        bc[j] = (j < 32) ? bmu[j] : bls[j - 32];
    }
    __syncthreads();

    int wave = threadIdx.x >> 6, lane = threadIdx.x & 63;
    int n = blockIdx.x * 4 + wave;   // N = 100000 = 25000 * 4, exact
    if (n >= N) return;
    int start = row[n], end = rend[n];
    float acc = 0.f;
    for (int j0 = start; j0 < end; j0 += 64) {
        int cnt = min(64, end - j0);
        int s = (lane < cnt) ? csr[j0 + lane] : 0;
        float ds = (lane < cnt) ? dinv[s] : 0.f;
        for (int j = 0; j < cnt; ++j) {
            int sj = __shfl(s, j);
            float dsj = __shfl(ds, j);
            acc += h[(size_t)sj * HID + lane] * dsj;
        }
    }
    float di = dinv[n];
    float abar = acc * di + h[(size_t)n * HID + lane] * di * di;
    ab[wave][lane] = abar;           // wave-local: no __syncthreads needed
    float acc2 = bc[lane];
#pragma unroll 16
    for (int k = 0; k < HID; ++k) acc2 += ab[wave][k] * Wc[k * 64 + lane];
    int which = lane >> 5, o = lane & 31;
    out[(size_t)which * N * 32 + (size_t)n * 32 + o] = acc2;
}

// ---------------------------------------------------------------------------
extern "C" void kernel_launch(void* const* d_in, const int* in_sizes, int n_in,
                              void* d_out, int out_size, void* d_ws, size_t ws_size,
                              hipStream_t stream) {
    const float* x   = (const float*)d_in[0];
    const int*   ei  = (const int*)d_in[1];
    const float* W1  = (const float*)d_in[2];
    const float* b1  = (const float*)d_in[3];
    const float* Wmu = (const float*)d_in[4];
    const float* bmu = (const float*)d_in[5];
    const float* Wls = (const float*)d_in[6];
    const float* bls = (const float*)d_in[7];
    int N = in_sizes[0] / FIN;
    int E = in_sizes[1] / 2;
    const int* src = ei;
    const int* dst = ei + E;
    float* out = (float*)d_out;

    // ws layout (all 4-byte elems):
    // deg[N] | dinv[N] | row[N] | cursor[N] | partials[128] | csr[E] | bufA[N*64] | bufB[N*64]
    int*   deg      = (int*)d_ws;
    float* dinv     = (float*)(deg + N);
    int*   row      = (int*)(dinv + N);
    int*   cursor   = row + N;
    int*   partials = cursor + N;
    int*   csr      = partials + 128;
    float* bufA     = (float*)(csr + E);            // h0
    float* bufB     = bufA + (size_t)N * HID;       // h

    int nb = (N + SCAN_BS - 1) / SCAN_BS;           // 98

    hipMemsetAsync(deg, 0, (size_t)N * sizeof(int), stream);
    count_deg<<<(E + 255) / 256, 256, 0, stream>>>(dst, deg, E);
    scan_blocks<<<nb, SCAN_BS, 0, stream>>>(deg, row, partials, N);
    scan_partials<<<1, 128, 0, stream>>>(partials, nb);
    finalize_ptr<<<(N + 255) / 256, 256, 0, stream>>>(deg, row, cursor, partials, dinv, N);
    fill_csr<<<(E + 255) / 256, 256, 0, stream>>>(src, dst, cursor, csr, E);

    gemm1<<<1024, 256, 0, stream>>>(x, W1, bufA, N);

    pull1<<<(N + 3) / 4, 256, 0, stream>>>(bufA, row, cursor, csr, dinv, b1, bufB, N);
    pull2_final<<<(N + 3) / 4, 256, 0, stream>>>(bufB, row, cursor, csr, dinv,
                                                 Wmu, bmu, Wls, bls, out, N);
}

// Round 3
// 480.833 us; speedup vs baseline: 2.0085x; 1.1710x over previous
//
#include <hip/hip_runtime.h>

#define FIN 128
#define HID 64
#define SCAN_BS 1024

// ---------------------------------------------------------------- degree ----
__global__ void count_deg(const int* __restrict__ dst, int* __restrict__ deg, int E) {
    int e = blockIdx.x * 256 + threadIdx.x;
    if (e < E) atomicAdd(&deg[dst[e]], 1);
}

// ------------------------------------------------- prefix scan (3 kernels) --
__global__ void scan_blocks(const int* __restrict__ deg, int* __restrict__ row_ex,
                            int* __restrict__ partials, int N) {
    __shared__ int s[SCAN_BS];
    int t = threadIdx.x;
    int i = blockIdx.x * SCAN_BS + t;
    int v = (i < N) ? deg[i] : 0;
    s[t] = v;
    __syncthreads();
    for (int off = 1; off < SCAN_BS; off <<= 1) {
        int a = (t >= off) ? s[t - off] : 0;
        __syncthreads();
        s[t] += a;
        __syncthreads();
    }
    if (i < N) row_ex[i] = s[t] - v;            // block-local exclusive
    if (t == SCAN_BS - 1) partials[blockIdx.x] = s[t];
}

__global__ void scan_partials(int* __restrict__ partials, int nb) {
    __shared__ int s[128];
    int t = threadIdx.x;
    int v = (t < nb) ? partials[t] : 0;
    s[t] = v;
    __syncthreads();
    for (int off = 1; off < 128; off <<= 1) {
        int a = (t >= off) ? s[t - off] : 0;
        __syncthreads();
        s[t] += a;
        __syncthreads();
    }
    if (t < nb) partials[t] = s[t] - v;          // exclusive
}

__global__ void finalize_ptr(const int* __restrict__ deg, int* __restrict__ row_ex,
                             int* __restrict__ cursor, const int* __restrict__ partials,
                             float* __restrict__ dinv, int N) {
    int i = blockIdx.x * 256 + threadIdx.x;
    if (i >= N) return;
    int r = row_ex[i] + partials[i >> 10];
    row_ex[i] = r;      // row start
    cursor[i] = r;      // fill cursor; after fill_csr it equals row end
    dinv[i] = rsqrtf((float)deg[i] + 1.0f);
}

// ------------------------------------------------------------- CSR fill -----
__global__ void fill_csr(const int* __restrict__ src, const int* __restrict__ dst,
                         int* __restrict__ cursor, int* __restrict__ csr, int E) {
    int e = blockIdx.x * 256 + threadIdx.x;
    if (e >= E) return;
    int d = dst[e];
    int p = atomicAdd(&cursor[d], 1);
    csr[p] = src[e];
}

// ---------------------------------------- h0' = (x @ W1) * dinv[n]  (pre-scaled)
__global__ void gemm1(const float* __restrict__ x, const float* __restrict__ W1,
                      const float* __restrict__ dinv, float* __restrict__ h0, int N) {
    __shared__ float Ws[FIN * HID];
    __shared__ float xs[16 * FIN];
    const float4* W4 = (const float4*)W1;
    float4* Ws4 = (float4*)Ws;
#pragma unroll
    for (int j = 0; j < 8; ++j) Ws4[threadIdx.x + 256 * j] = W4[threadIdx.x + 256 * j];
    __syncthreads();

    int f0 = threadIdx.x & 31, f1 = f0 + 32;
    int slot = threadIdx.x >> 5;
    int n0 = slot * 2, n1 = n0 + 1;
    int ntiles = N >> 4;
    for (int tile = blockIdx.x; tile < ntiles; tile += gridDim.x) {
        int base = tile << 4;
        const float4* xg = (const float4*)(x + (size_t)base * FIN);
        float4* xs4 = (float4*)xs;
        xs4[threadIdx.x]       = xg[threadIdx.x];
        xs4[threadIdx.x + 256] = xg[threadIdx.x + 256];
        __syncthreads();
        float a00 = 0.f, a01 = 0.f, a10 = 0.f, a11 = 0.f;
#pragma unroll 8
        for (int k = 0; k < FIN; ++k) {
            float w0 = Ws[k * HID + f0], w1 = Ws[k * HID + f1];
            float x0 = xs[n0 * FIN + k], x1 = xs[n1 * FIN + k];
            a00 += x0 * w0; a01 += x0 * w1;
            a10 += x1 * w0; a11 += x1 * w1;
        }
        float d0 = dinv[base + n0], d1 = dinv[base + n1];
        size_t r0 = (size_t)(base + n0) * HID, r1 = (size_t)(base + n1) * HID;
        h0[r0 + f0] = a00 * d0; h0[r0 + f1] = a01 * d0;
        h0[r1 + f0] = a10 * d1; h0[r1 + f1] = a11 * d1;
        __syncthreads();
    }
}

// ---- pull pass 1: h' = relu(dinv[d]*(Σ h0'[s] + h0'[d]) + b1) * dinv[d]
// wave per node, lane = feature. Indices are wave-uniform (scalar loads);
// 4 independent accumulators keep gathers pipelined.
__global__ void pull1(const float* __restrict__ hp, const int* __restrict__ row,
                      const int* __restrict__ rend, const int* __restrict__ csr,
                      const float* __restrict__ dinv, const float* __restrict__ b1,
                      float* __restrict__ hout, int N) {
    int wave = threadIdx.x >> 6, lane = threadIdx.x & 63;
    int n = blockIdx.x * 4 + wave;
    if (n >= N) return;
    int start = __builtin_amdgcn_readfirstlane(row[n]);
    int end   = __builtin_amdgcn_readfirstlane(rend[n]);
    float a0 = 0.f, a1 = 0.f, a2 = 0.f, a3 = 0.f;
    int j = start;
    for (; j + 4 <= end; j += 4) {
        int s0 = csr[j], s1 = csr[j + 1], s2 = csr[j + 2], s3 = csr[j + 3];
        a0 += hp[(size_t)s0 * HID + lane];
        a1 += hp[(size_t)s1 * HID + lane];
        a2 += hp[(size_t)s2 * HID + lane];
        a3 += hp[(size_t)s3 * HID + lane];
    }
    for (; j < end; ++j) {
        int s = csr[j];
        a0 += hp[(size_t)s * HID + lane];
    }
    float acc = (a0 + a1) + (a2 + a3) + hp[(size_t)n * HID + lane];
    float di = dinv[n];
    float v = di * acc + b1[lane];
    v = v > 0.f ? v : 0.f;
    hout[(size_t)n * HID + lane] = v * di;
}

// ---- pull pass 2 + output matvecs, fused.
// abar = dinv[d]*(Σ h'[s] + h'[d]) ; out = [abar@Wmu+bmu | abar@Wls+bls]
__global__ void pull2_final(const float* __restrict__ hp, const int* __restrict__ row,
                            const int* __restrict__ rend, const int* __restrict__ csr,
                            const float* __restrict__ dinv,
                            const float* __restrict__ Wmu, const float* __restrict__ bmu,
                            const float* __restrict__ Wls, const float* __restrict__ bls,
                            float* __restrict__ out, int N) {
    __shared__ float Wc[HID * 64];
    __shared__ float bc[64];
    __shared__ float ab[4][HID];
    for (int idx = threadIdx.x; idx < HID * 64; idx += 256) {
        int k = idx >> 6, j = idx & 63;
        Wc[idx] = (j < 32) ? Wmu[k * 32 + j] : Wls[k * 32 + (j - 32)];
    }
    if (threadIdx.x < 64) {
        int j = threadIdx.x;
        bc[j] = (j < 32) ? bmu[j] : bls[j - 32];
    }
    __syncthreads();

    int wave = threadIdx.x >> 6, lane = threadIdx.x & 63;
    int n = blockIdx.x * 4 + wave;
    if (n >= N) return;
    int start = __builtin_amdgcn_readfirstlane(row[n]);
    int end   = __builtin_amdgcn_readfirstlane(rend[n]);
    float a0 = 0.f, a1 = 0.f, a2 = 0.f, a3 = 0.f;
    int j = start;
    for (; j + 4 <= end; j += 4) {
        int s0 = csr[j], s1 = csr[j + 1], s2 = csr[j + 2], s3 = csr[j + 3];
        a0 += hp[(size_t)s0 * HID + lane];
        a1 += hp[(size_t)s1 * HID + lane];
        a2 += hp[(size_t)s2 * HID + lane];
        a3 += hp[(size_t)s3 * HID + lane];
    }
    for (; j < end; ++j) {
        int s = csr[j];
        a0 += hp[(size_t)s * HID + lane];
    }
    float acc = (a0 + a1) + (a2 + a3) + hp[(size_t)n * HID + lane];
    float abar = dinv[n] * acc;
    ab[wave][lane] = abar;           // wave-local: no __syncthreads needed
    float acc2 = bc[lane];
#pragma unroll 16
    for (int k = 0; k < HID; ++k) acc2 += ab[wave][k] * Wc[k * 64 + lane];
    int which = lane >> 5, o = lane & 31;
    out[(size_t)which * N * 32 + (size_t)n * 32 + o] = acc2;
}

// ---------------------------------------------------------------------------
extern "C" void kernel_launch(void* const* d_in, const int* in_sizes, int n_in,
                              void* d_out, int out_size, void* d_ws, size_t ws_size,
                              hipStream_t stream) {
    const float* x   = (const float*)d_in[0];
    const int*   ei  = (const int*)d_in[1];
    const float* W1  = (const float*)d_in[2];
    const float* b1  = (const float*)d_in[3];
    const float* Wmu = (const float*)d_in[4];
    const float* bmu = (const float*)d_in[5];
    const float* Wls = (const float*)d_in[6];
    const float* bls = (const float*)d_in[7];
    int N = in_sizes[0] / FIN;
    int E = in_sizes[1] / 2;
    const int* src = ei;
    const int* dst = ei + E;
    float* out = (float*)d_out;

    // ws layout (all 4-byte elems):
    // deg[N] | dinv[N] | row[N] | cursor[N] | partials[128] | csr[E] | bufA[N*64] | bufB[N*64]
    int*   deg      = (int*)d_ws;
    float* dinv     = (float*)(deg + N);
    int*   row      = (int*)(dinv + N);
    int*   cursor   = row + N;
    int*   partials = cursor + N;
    int*   csr      = partials + 128;
    float* bufA     = (float*)(csr + E);            // h0'
    float* bufB     = bufA + (size_t)N * HID;       // h'

    int nb = (N + SCAN_BS - 1) / SCAN_BS;           // 98

    hipMemsetAsync(deg, 0, (size_t)N * sizeof(int), stream);
    count_deg<<<(E + 255) / 256, 256, 0, stream>>>(dst, deg, E);
    scan_blocks<<<nb, SCAN_BS, 0, stream>>>(deg, row, partials, N);
    scan_partials<<<1, 128, 0, stream>>>(partials, nb);
    finalize_ptr<<<(N + 255) / 256, 256, 0, stream>>>(deg, row, cursor, partials, dinv, N);
    fill_csr<<<(E + 255) / 256, 256, 0, stream>>>(src, dst, cursor, csr, E);

    gemm1<<<1024, 256, 0, stream>>>(x, W1, dinv, bufA, N);

    pull1<<<(N + 3) / 4, 256, 0, stream>>>(bufA, row, cursor, csr, dinv, b1, bufB, N);
    pull2_final<<<(N + 3) / 4, 256, 0, stream>>>(bufB, row, cursor, csr, dinv,
                                                 Wmu, bmu, Wls, bls, out, N);
}

// Round 4
// 384.780 us; speedup vs baseline: 2.5099x; 1.2496x over previous
//
#include <hip/hip_runtime.h>

#define FIN 128
#define HID 64
#define BSN 128            // nodes per bucket
#define BSHIFT 7
#define SRCBITS 20         // src fits in 20 bits (N < 1M)
#define EPB 8192           // edges per binning block

// ---------------- bucket histogram (counts into bcur) ----------------------
__global__ void bin_count(const int* __restrict__ dst, int* __restrict__ bcnt,
                          int E, int B) {
    __shared__ int hist[1024];
    for (int i = threadIdx.x; i < 1024; i += 256) hist[i] = 0;
    __syncthreads();
    int base = blockIdx.x * EPB;
    int lim = min(base + EPB, E);
    for (int e = base + threadIdx.x; e < lim; e += 256)
        atomicAdd(&hist[dst[e] >> BSHIFT], 1);
    __syncthreads();
    for (int b = threadIdx.x; b < B; b += 256)
        if (hist[b]) atomicAdd(&bcnt[b], hist[b]);
}

// ---------------- scan bucket counts; bcnt becomes chunk cursor ------------
__global__ void scan_bkt(int* __restrict__ bcnt, int* __restrict__ bbase,
                         int E, int B) {
    __shared__ int s[1024];
    int t = threadIdx.x;
    int v = (t < B) ? bcnt[t] : 0;
    s[t] = v;
    __syncthreads();
    for (int off = 1; off < 1024; off <<= 1) {
        int a = (t >= off) ? s[t - off] : 0;
        __syncthreads();
        s[t] += a;
        __syncthreads();
    }
    if (t < B) { int ex = s[t] - v; bbase[t] = ex; bcnt[t] = ex; }
    if (t == 0) bbase[B] = E;
}

// ---------------- scatter packed records into per-bucket chunks ------------
__global__ void bin_fill(const int* __restrict__ src, const int* __restrict__ dst,
                         int* __restrict__ bcur, unsigned* __restrict__ rec, int E) {
    __shared__ int hist[1024];
    __shared__ int cbase[1024];
    for (int i = threadIdx.x; i < 1024; i += 256) hist[i] = 0;
    __syncthreads();
    int base = blockIdx.x * EPB;
    int lim = min(base + EPB, E);
    for (int e = base + threadIdx.x; e < lim; e += 256)
        atomicAdd(&hist[dst[e] >> BSHIFT], 1);
    __syncthreads();
    for (int b = threadIdx.x; b < 1024; b += 256) {
        int c = hist[b];
        cbase[b] = c ? atomicAdd(&bcur[b], c) : 0;   // one claim per (block,bucket)
    }
    __syncthreads();
    for (int i = threadIdx.x; i < 1024; i += 256) hist[i] = 0;
    __syncthreads();
    for (int e = base + threadIdx.x; e < lim; e += 256) {
        int d = dst[e];
        int b = d >> BSHIFT;
        int slot = atomicAdd(&hist[b], 1);           // LDS cursor (fast)
        rec[cbase[b] + slot] = (unsigned)src[e] | ((unsigned)(d & (BSN - 1)) << SRCBITS);
    }
}

// ------- per-bucket: count/scan 128 local nodes, emit row/rend/dinv/csr ----
__global__ void csr_build(const unsigned* __restrict__ rec, const int* __restrict__ bbase,
                          int* __restrict__ row, int* __restrict__ rend,
                          int* __restrict__ csr, float* __restrict__ dinv, int N) {
    __shared__ int cnt[BSN], excl[BSN], cur[BSN];
    int b = blockIdx.x, t = threadIdx.x;
    if (t < BSN) cnt[t] = 0;
    __syncthreads();
    int start = bbase[b], end = bbase[b + 1];
    for (int i = start + t; i < end; i += 256)
        atomicAdd(&cnt[rec[i] >> SRCBITS], 1);
    __syncthreads();
    if (t < BSN) excl[t] = cnt[t];
    __syncthreads();
    for (int off = 1; off < BSN; off <<= 1) {        // Hillis-Steele inclusive
        int a = 0;
        if (t < BSN && t >= off) a = excl[t - off];
        __syncthreads();
        if (t < BSN) excl[t] += a;
        __syncthreads();
    }
    if (t < BSN) {
        int inc = excl[t];
        int ex = inc - cnt[t];
        excl[t] = ex;                                // now exclusive
        cur[t] = 0;
        int n = b * BSN + t;
        if (n < N) {
            row[n]  = start + ex;
            rend[n] = start + inc;
            dinv[n] = rsqrtf((float)cnt[t] + 1.0f);
        }
    }
    __syncthreads();
    for (int i = start + t; i < end; i += 256) {     // hot 8KB region permute
        unsigned r = rec[i];
        int dl = r >> SRCBITS;
        int slot = atomicAdd(&cur[dl], 1);
        csr[start + excl[dl] + slot] = (int)(r & ((1u << SRCBITS) - 1));
    }
}

// ---------------------------------------- h0' = (x @ W1) * dinv[n] ----------
__global__ void gemm1(const float* __restrict__ x, const float* __restrict__ W1,
                      const float* __restrict__ dinv, float* __restrict__ h0, int N) {
    __shared__ float Ws[FIN * HID];
    __shared__ float xs[16 * FIN];
    const float4* W4 = (const float4*)W1;
    float4* Ws4 = (float4*)Ws;
#pragma unroll
    for (int j = 0; j < 8; ++j) Ws4[threadIdx.x + 256 * j] = W4[threadIdx.x + 256 * j];
    __syncthreads();

    int f0 = threadIdx.x & 31, f1 = f0 + 32;
    int slot = threadIdx.x >> 5;
    int n0 = slot * 2, n1 = n0 + 1;
    int ntiles = N >> 4;
    for (int tile = blockIdx.x; tile < ntiles; tile += gridDim.x) {
        int base = tile << 4;
        const float4* xg = (const float4*)(x + (size_t)base * FIN);
        float4* xs4 = (float4*)xs;
        xs4[threadIdx.x]       = xg[threadIdx.x];
        xs4[threadIdx.x + 256] = xg[threadIdx.x + 256];
        __syncthreads();
        float a00 = 0.f, a01 = 0.f, a10 = 0.f, a11 = 0.f;
#pragma unroll 8
        for (int k = 0; k < FIN; ++k) {
            float w0 = Ws[k * HID + f0], w1 = Ws[k * HID + f1];
            float x0 = xs[n0 * FIN + k], x1 = xs[n1 * FIN + k];
            a00 += x0 * w0; a01 += x0 * w1;
            a10 += x1 * w0; a11 += x1 * w1;
        }
        float d0 = dinv[base + n0], d1 = dinv[base + n1];
        size_t r0 = (size_t)(base + n0) * HID, r1 = (size_t)(base + n1) * HID;
        h0[r0 + f0] = a00 * d0; h0[r0 + f1] = a01 * d0;
        h0[r1 + f0] = a10 * d1; h0[r1 + f1] = a11 * d1;
        __syncthreads();
    }
}

// ---- pull pass 1: h' = relu(dinv[d]*(Σ h0'[s] + h0'[d]) + b1) * dinv[d]
__global__ void pull1(const float* __restrict__ hp, const int* __restrict__ row,
                      const int* __restrict__ rend, const int* __restrict__ csr,
                      const float* __restrict__ dinv, const float* __restrict__ b1,
                      float* __restrict__ hout, int N) {
    int wave = threadIdx.x >> 6, lane = threadIdx.x & 63;
    int n = blockIdx.x * 4 + wave;
    if (n >= N) return;
    int start = __builtin_amdgcn_readfirstlane(row[n]);
    int end   = __builtin_amdgcn_readfirstlane(rend[n]);
    float a0 = 0.f, a1 = 0.f, a2 = 0.f, a3 = 0.f;
    int j = start;
    for (; j + 4 <= end; j += 4) {
        int s0 = csr[j], s1 = csr[j + 1], s2 = csr[j + 2], s3 = csr[j + 3];
        a0 += hp[(size_t)s0 * HID + lane];
        a1 += hp[(size_t)s1 * HID + lane];
        a2 += hp[(size_t)s2 * HID + lane];
        a3 += hp[(size_t)s3 * HID + lane];
    }
    for (; j < end; ++j) {
        int s = csr[j];
        a0 += hp[(size_t)s * HID + lane];
    }
    float acc = (a0 + a1) + (a2 + a3) + hp[(size_t)n * HID + lane];
    float di = dinv[n];
    float v = di * acc + b1[lane];
    v = v > 0.f ? v : 0.f;
    hout[(size_t)n * HID + lane] = v * di;
}

// ---- pull pass 2 + dual output matvec, fused.
__global__ void pull2_final(const float* __restrict__ hp, const int* __restrict__ row,
                            const int* __restrict__ rend, const int* __restrict__ csr,
                            const float* __restrict__ dinv,
                            const float* __restrict__ Wmu, const float* __restrict__ bmu,
                            const float* __restrict__ Wls, const float* __restrict__ bls,
                            float* __restrict__ out, int N) {
    __shared__ float Wc[HID * 64];
    __shared__ float bc[64];
    __shared__ float ab[4][HID];
    for (int idx = threadIdx.x; idx < HID * 64; idx += 256) {
        int k = idx >> 6, j = idx & 63;
        Wc[idx] = (j < 32) ? Wmu[k * 32 + j] : Wls[k * 32 + (j - 32)];
    }
    if (threadIdx.x < 64) {
        int j = threadIdx.x;
        bc[j] = (j < 32) ? bmu[j] : bls[j - 32];
    }
    __syncthreads();

    int wave = threadIdx.x >> 6, lane = threadIdx.x & 63;
    int n = blockIdx.x * 4 + wave;
    if (n >= N) return;
    int start = __builtin_amdgcn_readfirstlane(row[n]);
    int end   = __builtin_amdgcn_readfirstlane(rend[n]);
    float a0 = 0.f, a1 = 0.f, a2 = 0.f, a3 = 0.f;
    int j = start;
    for (; j + 4 <= end; j += 4) {
        int s0 = csr[j], s1 = csr[j + 1], s2 = csr[j + 2], s3 = csr[j + 3];
        a0 += hp[(size_t)s0 * HID + lane];
        a1 += hp[(size_t)s1 * HID + lane];
        a2 += hp[(size_t)s2 * HID + lane];
        a3 += hp[(size_t)s3 * HID + lane];
    }
    for (; j < end; ++j) {
        int s = csr[j];
        a0 += hp[(size_t)s * HID + lane];
    }
    float acc = (a0 + a1) + (a2 + a3) + hp[(size_t)n * HID + lane];
    float abar = dinv[n] * acc;
    ab[wave][lane] = abar;           // wave-local
    float acc2 = bc[lane];
#pragma unroll 16
    for (int k = 0; k < HID; ++k) acc2 += ab[wave][k] * Wc[k * 64 + lane];
    int which = lane >> 5, o = lane & 31;
    out[(size_t)which * N * 32 + (size_t)n * 32 + o] = acc2;
}

// ---------------------------------------------------------------------------
extern "C" void kernel_launch(void* const* d_in, const int* in_sizes, int n_in,
                              void* d_out, int out_size, void* d_ws, size_t ws_size,
                              hipStream_t stream) {
    const float* x   = (const float*)d_in[0];
    const int*   ei  = (const int*)d_in[1];
    const float* W1  = (const float*)d_in[2];
    const float* b1  = (const float*)d_in[3];
    const float* Wmu = (const float*)d_in[4];
    const float* bmu = (const float*)d_in[5];
    const float* Wls = (const float*)d_in[6];
    const float* bls = (const float*)d_in[7];
    int N = in_sizes[0] / FIN;
    int E = in_sizes[1] / 2;
    const int* src = ei;
    const int* dst = ei + E;
    float* out = (float*)d_out;

    int B = (N + BSN - 1) / BSN;            // 782 buckets
    int nbin = (E + EPB - 1) / EPB;         // 196 binning blocks

    // ws layout (4-byte elems):
    // dinv[N] | row[N] | rend[N] | bbase[B+1] | bcur[B] | csr[E] | bufA[N*64] |
    // region2[max(E, N*64)]  (recbuf during build, then bufB = h')
    float* dinv  = (float*)d_ws;
    int*   row   = (int*)(dinv + N);
    int*   rend  = row + N;
    int*   bbase = rend + N;
    int*   bcur  = bbase + (B + 1);
    int*   csr   = bcur + B;
    float* bufA  = (float*)(csr + E);               // h0'
    float* region2 = bufA + (size_t)N * HID;
    unsigned* rec  = (unsigned*)region2;            // E recs (dead after csr_build)
    float* bufB    = region2;                       // h' (N*64)

    hipMemsetAsync(bcur, 0, (size_t)B * sizeof(int), stream);
    bin_count<<<nbin, 256, 0, stream>>>(dst, bcur, E, B);
    scan_bkt<<<1, 1024, 0, stream>>>(bcur, bbase, E, B);
    bin_fill<<<nbin, 256, 0, stream>>>(src, dst, bcur, rec, E);
    csr_build<<<B, 256, 0, stream>>>(rec, bbase, row, rend, csr, dinv, N);

    gemm1<<<1024, 256, 0, stream>>>(x, W1, dinv, bufA, N);

    pull1<<<(N + 3) / 4, 256, 0, stream>>>(bufA, row, rend, csr, dinv, b1, bufB, N);
    pull2_final<<<(N + 3) / 4, 256, 0, stream>>>(bufB, row, rend, csr, dinv,
                                                 Wmu, bmu, Wls, bls, out, N);
}

// Round 5
// 340.489 us; speedup vs baseline: 2.8363x; 1.1301x over previous
//
#include <hip/hip_runtime.h>
#include <hip/hip_bf16.h>

#define FIN 128
#define HID 64
#define BSN 128            // nodes per bucket
#define BSHIFT 7
#define SRCBITS 20         // src fits in 20 bits (N < 1M)
#define EPB 8192           // edges per binning block

__device__ __forceinline__ float bf2f(unsigned short u) {
    union { unsigned int i; float f; } c;
    c.i = ((unsigned int)u) << 16;
    return c.f;
}

__device__ __forceinline__ unsigned short f2bf(float f) {
    union { float f; unsigned int i; } c;
    c.f = f;
    unsigned int u = c.i;
    unsigned int r = (u + 0x7FFFu + ((u >> 16) & 1u)) >> 16;   // RNE
    return (unsigned short)r;
}

// ---------------- bucket histogram (counts into bcur) ----------------------
__global__ void bin_count(const int* __restrict__ dst, int* __restrict__ bcnt,
                          int E, int B) {
    __shared__ int hist[1024];
    for (int i = threadIdx.x; i < 1024; i += 256) hist[i] = 0;
    __syncthreads();
    int base = blockIdx.x * EPB;
    int lim = min(base + EPB, E);
    for (int e = base + threadIdx.x; e < lim; e += 256)
        atomicAdd(&hist[dst[e] >> BSHIFT], 1);
    __syncthreads();
    for (int b = threadIdx.x; b < B; b += 256)
        if (hist[b]) atomicAdd(&bcnt[b], hist[b]);
}

// ---------------- scan bucket counts; bcnt becomes chunk cursor ------------
__global__ void scan_bkt(int* __restrict__ bcnt, int* __restrict__ bbase,
                         int E, int B) {
    __shared__ int s[1024];
    int t = threadIdx.x;
    int v = (t < B) ? bcnt[t] : 0;
    s[t] = v;
    __syncthreads();
    for (int off = 1; off < 1024; off <<= 1) {
        int a = (t >= off) ? s[t - off] : 0;
        __syncthreads();
        s[t] += a;
        __syncthreads();
    }
    if (t < B) { int ex = s[t] - v; bbase[t] = ex; bcnt[t] = ex; }
    if (t == 0) bbase[B] = E;
}

// ---------------- scatter packed records into per-bucket chunks ------------
__global__ void bin_fill(const int* __restrict__ src, const int* __restrict__ dst,
                         int* __restrict__ bcur, unsigned* __restrict__ rec, int E) {
    __shared__ int hist[1024];
    __shared__ int cbase[1024];
    for (int i = threadIdx.x; i < 1024; i += 256) hist[i] = 0;
    __syncthreads();
    int base = blockIdx.x * EPB;
    int lim = min(base + EPB, E);
    for (int e = base + threadIdx.x; e < lim; e += 256)
        atomicAdd(&hist[dst[e] >> BSHIFT], 1);
    __syncthreads();
    for (int b = threadIdx.x; b < 1024; b += 256) {
        int c = hist[b];
        cbase[b] = c ? atomicAdd(&bcur[b], c) : 0;   // one claim per (block,bucket)
    }
    __syncthreads();
    for (int i = threadIdx.x; i < 1024; i += 256) hist[i] = 0;
    __syncthreads();
    for (int e = base + threadIdx.x; e < lim; e += 256) {
        int d = dst[e];
        int b = d >> BSHIFT;
        int slot = atomicAdd(&hist[b], 1);           // LDS cursor (fast)
        rec[cbase[b] + slot] = (unsigned)src[e] | ((unsigned)(d & (BSN - 1)) << SRCBITS);
    }
}

// ------- per-bucket: count/scan 128 local nodes, emit row/rend/dinv/csr ----
__global__ void csr_build(const unsigned* __restrict__ rec, const int* __restrict__ bbase,
                          int* __restrict__ row, int* __restrict__ rend,
                          int* __restrict__ csr, float* __restrict__ dinv, int N) {
    __shared__ int cnt[BSN], excl[BSN], cur[BSN];
    int b = blockIdx.x, t = threadIdx.x;
    if (t < BSN) cnt[t] = 0;
    __syncthreads();
    int start = bbase[b], end = bbase[b + 1];
    for (int i = start + t; i < end; i += 256)
        atomicAdd(&cnt[rec[i] >> SRCBITS], 1);
    __syncthreads();
    if (t < BSN) excl[t] = cnt[t];
    __syncthreads();
    for (int off = 1; off < BSN; off <<= 1) {        // Hillis-Steele inclusive
        int a = 0;
        if (t < BSN && t >= off) a = excl[t - off];
        __syncthreads();
        if (t < BSN) excl[t] += a;
        __syncthreads();
    }
    if (t < BSN) {
        int inc = excl[t];
        int ex = inc - cnt[t];
        excl[t] = ex;                                // now exclusive
        cur[t] = 0;
        int n = b * BSN + t;
        if (n < N) {
            row[n]  = start + ex;
            rend[n] = start + inc;
            dinv[n] = rsqrtf((float)cnt[t] + 1.0f);
        }
    }
    __syncthreads();
    for (int i = start + t; i < end; i += 256) {     // hot 8KB region permute
        unsigned r = rec[i];
        int dl = r >> SRCBITS;
        int slot = atomicAdd(&cur[dl], 1);
        csr[start + excl[dl] + slot] = (int)(r & ((1u << SRCBITS) - 1));
    }
}

// -------------------------- h0' = bf16((x @ W1) * dinv[n]) ------------------
__global__ void gemm1(const float* __restrict__ x, const float* __restrict__ W1,
                      const float* __restrict__ dinv, unsigned short* __restrict__ h0,
                      int N) {
    __shared__ float Ws[FIN * HID];
    __shared__ float xs[16 * FIN];
    const float4* W4 = (const float4*)W1;
    float4* Ws4 = (float4*)Ws;
#pragma unroll
    for (int j = 0; j < 8; ++j) Ws4[threadIdx.x + 256 * j] = W4[threadIdx.x + 256 * j];
    __syncthreads();

    int f0 = threadIdx.x & 31, f1 = f0 + 32;
    int slot = threadIdx.x >> 5;
    int n0 = slot * 2, n1 = n0 + 1;
    int ntiles = N >> 4;
    for (int tile = blockIdx.x; tile < ntiles; tile += gridDim.x) {
        int base = tile << 4;
        const float4* xg = (const float4*)(x + (size_t)base * FIN);
        float4* xs4 = (float4*)xs;
        xs4[threadIdx.x]       = xg[threadIdx.x];
        xs4[threadIdx.x + 256] = xg[threadIdx.x + 256];
        __syncthreads();
        float a00 = 0.f, a01 = 0.f, a10 = 0.f, a11 = 0.f;
#pragma unroll 8
        for (int k = 0; k < FIN; ++k) {
            float w0 = Ws[k * HID + f0], w1 = Ws[k * HID + f1];
            float x0 = xs[n0 * FIN + k], x1 = xs[n1 * FIN + k];
            a00 += x0 * w0; a01 += x0 * w1;
            a10 += x1 * w0; a11 += x1 * w1;
        }
        float d0 = dinv[base + n0], d1 = dinv[base + n1];
        size_t r0 = (size_t)(base + n0) * HID, r1 = (size_t)(base + n1) * HID;
        h0[r0 + f0] = f2bf(a00 * d0); h0[r0 + f1] = f2bf(a01 * d0);
        h0[r1 + f0] = f2bf(a10 * d1); h0[r1 + f1] = f2bf(a11 * d1);
        __syncthreads();
    }
}

// ---- pull pass 1: h' = bf16(relu(dinv[d]*(Σ h0'[s] + h0'[d]) + b1) * dinv[d])
// wave per node, lane = feature; wave-uniform scalar indices; 4 accumulators.
__global__ void pull1(const unsigned short* __restrict__ hp, const int* __restrict__ row,
                      const int* __restrict__ rend, const int* __restrict__ csr,
                      const float* __restrict__ dinv, const float* __restrict__ b1,
                      unsigned short* __restrict__ hout, int N) {
    int wave = threadIdx.x >> 6, lane = threadIdx.x & 63;
    int n = blockIdx.x * 4 + wave;
    if (n >= N) return;
    int start = __builtin_amdgcn_readfirstlane(row[n]);
    int end   = __builtin_amdgcn_readfirstlane(rend[n]);
    float a0 = 0.f, a1 = 0.f, a2 = 0.f, a3 = 0.f;
    int j = start;
    for (; j + 4 <= end; j += 4) {
        int s0 = csr[j], s1 = csr[j + 1], s2 = csr[j + 2], s3 = csr[j + 3];
        a0 += bf2f(hp[(size_t)s0 * HID + lane]);
        a1 += bf2f(hp[(size_t)s1 * HID + lane]);
        a2 += bf2f(hp[(size_t)s2 * HID + lane]);
        a3 += bf2f(hp[(size_t)s3 * HID + lane]);
    }
    for (; j < end; ++j) {
        int s = csr[j];
        a0 += bf2f(hp[(size_t)s * HID + lane]);
    }
    float acc = (a0 + a1) + (a2 + a3) + bf2f(hp[(size_t)n * HID + lane]);
    float di = dinv[n];
    float v = di * acc + b1[lane];
    v = v > 0.f ? v : 0.f;
    hout[(size_t)n * HID + lane] = f2bf(v * di);
}

// ---- pull pass 2 + dual output matvec, fused.
__global__ void pull2_final(const unsigned short* __restrict__ hp, const int* __restrict__ row,
                            const int* __restrict__ rend, const int* __restrict__ csr,
                            const float* __restrict__ dinv,
                            const float* __restrict__ Wmu, const float* __restrict__ bmu,
                            const float* __restrict__ Wls, const float* __restrict__ bls,
                            float* __restrict__ out, int N) {
    __shared__ float Wc[HID * 64];
    __shared__ float bc[64];
    __shared__ float ab[4][HID];
    for (int idx = threadIdx.x; idx < HID * 64; idx += 256) {
        int k = idx >> 6, j = idx & 63;
        Wc[idx] = (j < 32) ? Wmu[k * 32 + j] : Wls[k * 32 + (j - 32)];
    }
    if (threadIdx.x < 64) {
        int j = threadIdx.x;
        bc[j] = (j < 32) ? bmu[j] : bls[j - 32];
    }
    __syncthreads();

    int wave = threadIdx.x >> 6, lane = threadIdx.x & 63;
    int n = blockIdx.x * 4 + wave;
    if (n >= N) return;
    int start = __builtin_amdgcn_readfirstlane(row[n]);
    int end   = __builtin_amdgcn_readfirstlane(rend[n]);
    float a0 = 0.f, a1 = 0.f, a2 = 0.f, a3 = 0.f;
    int j = start;
    for (; j + 4 <= end; j += 4) {
        int s0 = csr[j], s1 = csr[j + 1], s2 = csr[j + 2], s3 = csr[j + 3];
        a0 += bf2f(hp[(size_t)s0 * HID + lane]);
        a1 += bf2f(hp[(size_t)s1 * HID + lane]);
        a2 += bf2f(hp[(size_t)s2 * HID + lane]);
        a3 += bf2f(hp[(size_t)s3 * HID + lane]);
    }
    for (; j < end; ++j) {
        int s = csr[j];
        a0 += bf2f(hp[(size_t)s * HID + lane]);
    }
    float acc = (a0 + a1) + (a2 + a3) + bf2f(hp[(size_t)n * HID + lane]);
    float abar = dinv[n] * acc;
    ab[wave][lane] = abar;           // wave-local
    float acc2 = bc[lane];
#pragma unroll 16
    for (int k = 0; k < HID; ++k) acc2 += ab[wave][k] * Wc[k * 64 + lane];
    int which = lane >> 5, o = lane & 31;
    out[(size_t)which * N * 32 + (size_t)n * 32 + o] = acc2;
}

// ---------------------------------------------------------------------------
extern "C" void kernel_launch(void* const* d_in, const int* in_sizes, int n_in,
                              void* d_out, int out_size, void* d_ws, size_t ws_size,
                              hipStream_t stream) {
    const float* x   = (const float*)d_in[0];
    const int*   ei  = (const int*)d_in[1];
    const float* W1  = (const float*)d_in[2];
    const float* b1  = (const float*)d_in[3];
    const float* Wmu = (const float*)d_in[4];
    const float* bmu = (const float*)d_in[5];
    const float* Wls = (const float*)d_in[6];
    const float* bls = (const float*)d_in[7];
    int N = in_sizes[0] / FIN;
    int E = in_sizes[1] / 2;
    const int* src = ei;
    const int* dst = ei + E;
    float* out = (float*)d_out;

    int B = (N + BSN - 1) / BSN;            // 782 buckets
    int nbin = (E + EPB - 1) / EPB;         // 196 binning blocks

    // ws layout (bytes):
    // dinv[N f32] | row[N i32] | rend[N i32] | bbase[B+1] | bcur[B] | csr[E i32] |
    // bufA[N*64 bf16] | region2[max(E*4, N*64*2) bytes] (rec during build, then bufB)
    float* dinv  = (float*)d_ws;
    int*   row   = (int*)(dinv + N);
    int*   rend  = row + N;
    int*   bbase = rend + N;
    int*   bcur  = bbase + (B + 1);
    int*   csr   = bcur + B;
    unsigned short* bufA = (unsigned short*)(csr + E);          // h0' bf16
    char* region2 = (char*)(bufA + (size_t)N * HID);
    unsigned* rec       = (unsigned*)region2;                   // E recs (dead after csr_build)
    unsigned short* bufB = (unsigned short*)region2;            // h' bf16

    hipMemsetAsync(bcur, 0, (size_t)B * sizeof(int), stream);
    bin_count<<<nbin, 256, 0, stream>>>(dst, bcur, E, B);
    scan_bkt<<<1, 1024, 0, stream>>>(bcur, bbase, E, B);
    bin_fill<<<nbin, 256, 0, stream>>>(src, dst, bcur, rec, E);
    csr_build<<<B, 256, 0, stream>>>(rec, bbase, row, rend, csr, dinv, N);

    gemm1<<<1024, 256, 0, stream>>>(x, W1, dinv, bufA, N);

    pull1<<<(N + 3) / 4, 256, 0, stream>>>(bufA, row, rend, csr, dinv, b1, bufB, N);
    pull2_final<<<(N + 3) / 4, 256, 0, stream>>>(bufB, row, rend, csr, dinv,
                                                 Wmu, bmu, Wls, bls, out, N);
}